// Round 13
// baseline (97.342 us; speedup 1.0000x reference)
//
#include <hip/hip_runtime.h>

#define NPTS 2048
#define CCH  256

// ws byte layout:
//   [0    .. 4095 ]  W_eff (256x3 f32) + b_eff (256 f32)
//   [4096 .. 6143 ]  starts: per batch 128 u32 slots (65 used)
//   [8192 .. 139263] scrd: float4[4][2048] cell-sorted (x,y,z,orig_idx_bits)
//   [1 MB ...]       scan-probe scratch
//   [2 MB ...]       epi-probe scratch
#define STARTS_OFF 4096
#define CRD_OFF    8192
#define SCAN_SCR   (1u << 20)
#define EPI_SCR    (2u << 20)

// ---- DPP cross-lane helpers ----
template <int CTRL>
__device__ __forceinline__ float dppf(float v) {
    return __int_as_float(__builtin_amdgcn_update_dpp(
        0, __float_as_int(v), CTRL, 0xF, 0xF, true));
}
__device__ __forceinline__ float row16_max(float v) {
    v = fmaxf(v, dppf<0xB1>(v));
    v = fmaxf(v, dppf<0x4E>(v));
    v = fmaxf(v, dppf<0x141>(v));
    v = fmaxf(v, dppf<0x140>(v));
    return v;
}
__device__ __forceinline__ float row16_sum(float v) {
    v += dppf<0xB1>(v);
    v += dppf<0x4E>(v);
    v += dppf<0x141>(v);
    v += dppf<0x140>(v);
    return v;
}
__device__ __forceinline__ float wave_sum(float v) {
    v = row16_sum(v);
    v += __shfl_xor(v, 16, 64);
    v += __shfl_xor(v, 32, 64);
    return v;
}
__device__ __forceinline__ int cell_coord(float v) {
    int c = (int)(v * 4.0f);
    return min(3, max(0, c));
}

// ---------------------------------------------------------------------------
// Fused prep + per-batch counting sort (R12 structure, unchanged).
// ---------------------------------------------------------------------------
__global__ __launch_bounds__(256) void prep_sort_kernel(
    const float* __restrict__ x,
    const float* __restrict__ w1, const float* __restrict__ b1,
    const float* __restrict__ w2, const float* __restrict__ b2,
    const float* __restrict__ w3, const float* __restrict__ b3,
    float* __restrict__ ws, int Bp)
{
    __shared__ float  w3row[2][CCH];
    __shared__ float4 wpart[2][4];
    __shared__ unsigned shist[64];
    __shared__ unsigned scur[64];

    int tid = threadIdx.x;

    if ((int)blockIdx.x < CCH / 2) {
        int o0 = blockIdx.x * 2, c = tid;
        float w3c0 = w3[(o0 + 0) * CCH + c];
        float w3c1 = w3[(o0 + 1) * CCH + c];
        w3row[0][c] = w3c0;
        w3row[1][c] = w3c1;
        __syncthreads();

        float a0 = 0.f, a1 = 0.f, a2 = 0.f, a3 = 0.f;
        float b0 = 0.f, b1p = 0.f, b2p = 0.f, b3p = 0.f;
        const float* w2c = w2 + c;
        for (int k = 0; k < CCH; k += 4) {
            float q0 = w2c[(k + 0) * CCH];
            float q1 = w2c[(k + 1) * CCH];
            float q2 = w2c[(k + 2) * CCH];
            float q3 = w2c[(k + 3) * CCH];
            a0 = fmaf(w3row[0][k + 0], q0, a0);
            a1 = fmaf(w3row[0][k + 1], q1, a1);
            a2 = fmaf(w3row[0][k + 2], q2, a2);
            a3 = fmaf(w3row[0][k + 3], q3, a3);
            b0  = fmaf(w3row[1][k + 0], q0, b0);
            b1p = fmaf(w3row[1][k + 1], q1, b1p);
            b2p = fmaf(w3row[1][k + 2], q2, b2p);
            b3p = fmaf(w3row[1][k + 3], q3, b3p);
        }
        float accA = (a0 + a1) + (a2 + a3);
        float accB = (b0 + b1p) + (b2p + b3p);

        float w1x = w1[c * 3 + 0], w1y = w1[c * 3 + 1], w1z = w1[c * 3 + 2];
        float b1c = b1[c], b2c = b2[c];

        float4 vA = make_float4(accA * w1x, accA * w1y, accA * w1z,
                                fmaf(accA, b1c, w3c0 * b2c));
        float4 vB = make_float4(accB * w1x, accB * w1y, accB * w1z,
                                fmaf(accB, b1c, w3c1 * b2c));
        vA.x = wave_sum(vA.x); vA.y = wave_sum(vA.y);
        vA.z = wave_sum(vA.z); vA.w = wave_sum(vA.w);
        vB.x = wave_sum(vB.x); vB.y = wave_sum(vB.y);
        vB.z = wave_sum(vB.z); vB.w = wave_sum(vB.w);
        if ((c & 63) == 0) {
            wpart[0][c >> 6] = vA;
            wpart[1][c >> 6] = vB;
        }
        __syncthreads();
        if (c < 2) {
            int o = o0 + c;
            float4 p0 = wpart[c][0], p1 = wpart[c][1], p2 = wpart[c][2], p3 = wpart[c][3];
            ws[o * 3 + 0] = (p0.x + p1.x) + (p2.x + p3.x);
            ws[o * 3 + 1] = (p0.y + p1.y) + (p2.y + p3.y);
            ws[o * 3 + 2] = (p0.z + p1.z) + (p2.z + p3.z);
            ws[3 * CCH + o] = (p0.w + p1.w) + (p2.w + p3.w) + b3[o];
        }
        return;
    }

    int b = blockIdx.x - CCH / 2;
    if (b >= Bp) return;
    const float* xb = x + (size_t)b * NPTS * 3;

    if (tid < 64) shist[tid] = 0;
    __syncthreads();

    float a[24];
#pragma unroll
    for (int j = 0; j < 6; ++j)
        *(float4*)(a + 4 * j) = ((const float4*)xb)[tid * 6 + j];

    int cl[8];
#pragma unroll
    for (int k = 0; k < 8; ++k) {
        cl[k] = (cell_coord(a[3 * k + 0]) << 4) |
                (cell_coord(a[3 * k + 1]) << 2) |
                 cell_coord(a[3 * k + 2]);
        atomicAdd(&shist[cl[k]], 1u);
    }
    __syncthreads();

    unsigned* stg = (unsigned*)((char*)ws + STARTS_OFF) + b * 128;
    if (tid < 64) {
        unsigned v = shist[tid];
        unsigned incl = v;
#pragma unroll
        for (int s = 1; s < 64; s <<= 1) {
            unsigned o = __shfl_up(incl, s, 64);
            if (tid >= s) incl += o;
        }
        unsigned excl = incl - v;
        scur[tid] = excl;
        stg[tid] = excl;
        if (tid == 63) stg[64] = NPTS;
    }
    __syncthreads();

    float4* crd = (float4*)((char*)ws + CRD_OFF) + (size_t)b * NPTS;
#pragma unroll
    for (int k = 0; k < 8; ++k) {
        unsigned pos = atomicAdd(&scur[cl[k]], 1u);
        crd[pos] = make_float4(a[3 * k + 0], a[3 * k + 1], a[3 * k + 2],
                               __uint_as_float((unsigned)(8 * tid + k)));
    }
}

// ---------------------------------------------------------------------------
// Main pointsift (R12 structure + 3-SLAB SCAN): for each x-cell a in
// [ccx-1,ccx+1]∩[0,3], scan ONE contiguous run covering y∈[bclo,bchi], all z.
// Extra candidates (z outside +-1 window) are provably filtered by d2:
// |dz| >= 0.25 => fl(d2) >= 0.0625 => invalid in both kernel and reference.
// ---------------------------------------------------------------------------
__global__ __launch_bounds__(256, 8) void pointsift_kernel(
    const float* __restrict__ x,
    const float* __restrict__ ws,
    float* __restrict__ out)
{
    __shared__ unsigned sstart[65];
    __shared__ unsigned long long soct[4][8];

    int tid = threadIdx.x;
    int batch = blockIdx.x & 3;
    int n0    = (blockIdx.x >> 2) * 4;
    const float* xb = x + (size_t)batch * NPTS * 3;
    const float4* crd = (const float4*)((const char*)ws + CRD_OFF) + (size_t)batch * NPTS;
    const unsigned* stg = (const unsigned*)((const char*)ws + STARTS_OFF) + batch * 128;

    if (tid < 65) sstart[tid] = stg[tid];

    int wave = tid >> 6;
    int lane = tid & 63;
    int n = n0 + wave;

    float3 cpt = *(const float3*)(xb + 3 * n);
    float cx = cpt.x, cy = cpt.y, cz = cpt.z;

    if (lane < 8)
        soct[wave][lane] = (0x7f800000ULL << 32) | (unsigned)n;

    __syncthreads();

    int ccx = cell_coord(cx), ccy = cell_coord(cy);
    int alo = ccx > 0 ? ccx - 1 : 0;
    int ahi = ccx < 3 ? ccx + 1 : 3;
    int bclo = ccy > 0 ? ccy - 1 : 0;
    int bchi = ccy < 3 ? ccy + 1 : 3;

    for (int a = alo; a <= ahi; ++a) {
        unsigned s0 = sstart[(a << 4) | (bclo << 2)];
        unsigned e0 = sstart[(a << 4) + (bchi << 2) + 4];
        for (unsigned pp = s0 + lane; pp < e0; pp += 64) {
            float4 p = crd[pp];
            float dx = p.x - cx, dy = p.y - cy, dz = p.z - cz;
            // bit-match numpy: (dx*dx + dy*dy) + dz*dz, no FMA contraction
            float d2 = __fadd_rn(__fadd_rn(__fmul_rn(dx, dx), __fmul_rn(dy, dy)),
                                 __fmul_rn(dz, dz));
            if ((d2 > 1e-10f) && (d2 < 0.0625f)) {
                // exact octant per reference: trunc(d+1.0) in {0,1}
                int oct = 4 * (int)(dx + 1.0f) + 2 * (int)(dy + 1.0f) + (int)(dz + 1.0f);
                unsigned long long key =
                    ((unsigned long long)__float_as_uint(d2) << 32) |
                    __float_as_uint(p.w);
                __hip_atomic_fetch_min(&soct[wave][oct], key,
                                       __ATOMIC_RELAXED,
                                       __HIP_MEMORY_SCOPE_WORKGROUP);
            }
        }
    }

    int nidx[8];
#pragma unroll
    for (int k = 0; k < 8; ++k)
        nidx[k] = (int)(unsigned)soct[wave][k];

    const float4* wsv = (const float4*)ws;
    float4 wa = wsv[lane * 3 + 0];
    float4 wb = wsv[lane * 3 + 1];
    float4 wc = wsv[lane * 3 + 2];
    float4 be = ((const float4*)(ws + 3 * CCH))[lane];
    float w[4][3] = {{wa.x, wa.y, wa.z}, {wa.w, wb.x, wb.y},
                     {wb.z, wb.w, wc.x}, {wc.y, wc.z, wc.w}};
    float bev[4] = {be.x, be.y, be.z, be.w};

    float m16[4];
#pragma unroll
    for (int i = 0; i < 4; ++i) m16[i] = -__builtin_inff();
#pragma unroll
    for (int k = 0; k < 8; ++k) {
        float3 p = *(const float3*)(xb + 3 * nidx[k]);
        float gx = p.x - cx, gy = p.y - cy, gz = p.z - cz;
#pragma unroll
        for (int q = 0; q < 4; ++q) {
            float h = fmaf(gx, w[q][0], fmaf(gy, w[q][1], fmaf(gz, w[q][2], bev[q])));
            m16[k >> 1] = fmaxf(m16[k >> 1], h);
        }
    }

    float t[4], u[4];
#pragma unroll
    for (int i = 0; i < 4; ++i) {
        m16[i] = row16_max(m16[i]);
        t[i] = fmaxf(m16[i], __shfl_xor(m16[i], 16, 64));
        u[i] = fmaxf(t[i], __shfl_xor(t[i], 32, 64));
    }

    float* op = out + ((size_t)batch * NPTS + n) * 21;
    if ((lane & 15) == 0) {
        int j = lane >> 4;
#pragma unroll
        for (int i = 0; i < 4; ++i)
            op[i * 4 + j] = m16[i];
    }
    if (lane == 0 || lane == 32) {
        int j2 = lane >> 5;
        op[16 + 0 * 2 + j2] = fmaxf(t[0], t[1]);
        op[16 + 1 * 2 + j2] = fmaxf(t[2], t[3]);
    }
    if (lane == 0) {
        op[20] = fmaxf(fmaxf(u[0], u[1]), fmaxf(u[2], u[3]));
    }
}

// ---------------------------------------------------------------------------
// PROBE 1: prologue + 3-slab scan + atomics only, x8 reps. Writes soct to
// ws scratch (never d_out). Measures the scan phase in isolation.
// ---------------------------------------------------------------------------
__global__ __launch_bounds__(256, 8) void scan_probe_kernel(
    const float* __restrict__ x, float* __restrict__ ws)
{
    __shared__ unsigned sstart[65];
    __shared__ unsigned long long soct[4][8];

    int tid = threadIdx.x;
    int batch = blockIdx.x & 3;
    int n0    = (blockIdx.x >> 2) * 4;
    const float* xb = x + (size_t)batch * NPTS * 3;
    const float4* crd = (const float4*)((const char*)ws + CRD_OFF) + (size_t)batch * NPTS;
    const unsigned* stg = (const unsigned*)((const char*)ws + STARTS_OFF) + batch * 128;

    if (tid < 65) sstart[tid] = stg[tid];

    int wave = tid >> 6;
    int lane = tid & 63;
    int n = n0 + wave;

    float3 cpt = *(const float3*)(xb + 3 * n);
    float cx = cpt.x, cy = cpt.y, cz = cpt.z;
    __syncthreads();

    int ccx = cell_coord(cx), ccy = cell_coord(cy);
    int alo = ccx > 0 ? ccx - 1 : 0;
    int ahi = ccx < 3 ? ccx + 1 : 3;
    int bclo = ccy > 0 ? ccy - 1 : 0;
    int bchi = ccy < 3 ? ccy + 1 : 3;

    unsigned long long* sc =
        (unsigned long long*)((char*)ws + SCAN_SCR) + (size_t)blockIdx.x * 32;

    for (int rep = 0; rep < 8; ++rep) {
        if (lane < 8)
            soct[wave][lane] = (0x7f800000ULL << 32) | (unsigned)n;
        asm volatile("" ::: "memory");

        for (int a = alo; a <= ahi; ++a) {
            unsigned s0 = sstart[(a << 4) | (bclo << 2)];
            unsigned e0 = sstart[(a << 4) + (bchi << 2) + 4];
            for (unsigned pp = s0 + lane; pp < e0; pp += 64) {
                float4 p = crd[pp];
                float dx = p.x - cx, dy = p.y - cy, dz = p.z - cz;
                float d2 = __fadd_rn(__fadd_rn(__fmul_rn(dx, dx), __fmul_rn(dy, dy)),
                                     __fmul_rn(dz, dz));
                if ((d2 > 1e-10f) && (d2 < 0.0625f)) {
                    int oct = 4 * (int)(dx + 1.0f) + 2 * (int)(dy + 1.0f) + (int)(dz + 1.0f);
                    unsigned long long key =
                        ((unsigned long long)__float_as_uint(d2) << 32) |
                        __float_as_uint(p.w);
                    __hip_atomic_fetch_min(&soct[wave][oct], key,
                                           __ATOMIC_RELAXED,
                                           __HIP_MEMORY_SCOPE_WORKGROUP);
                }
            }
        }
        asm volatile("" ::: "memory");
        if (lane < 8)
            sc[wave * 8 + lane] = soct[wave][lane];
        asm volatile("" ::: "memory");
    }
}

// ---------------------------------------------------------------------------
// PROBE 2: prologue + epilogue (gather + affine + SPP + 21-float store) with
// deterministic fake neighbor indices, x8 reps (rep-dependent indices block
// hoisting). Writes to ws scratch. Measures the epilogue phase in isolation.
// ---------------------------------------------------------------------------
__global__ __launch_bounds__(256, 8) void epi_probe_kernel(
    const float* __restrict__ x, float* __restrict__ ws)
{
    int tid = threadIdx.x;
    int batch = blockIdx.x & 3;
    int n0    = (blockIdx.x >> 2) * 4;
    const float* xb = x + (size_t)batch * NPTS * 3;

    int wave = tid >> 6;
    int lane = tid & 63;
    int n = n0 + wave;

    float3 cpt = *(const float3*)(xb + 3 * n);
    float cx = cpt.x, cy = cpt.y, cz = cpt.z;

    const float4* wsv = (const float4*)ws;
    float4 wa = wsv[lane * 3 + 0];
    float4 wb = wsv[lane * 3 + 1];
    float4 wc = wsv[lane * 3 + 2];
    float4 be = ((const float4*)(ws + 3 * CCH))[lane];
    float w[4][3] = {{wa.x, wa.y, wa.z}, {wa.w, wb.x, wb.y},
                     {wb.z, wb.w, wc.x}, {wc.y, wc.z, wc.w}};
    float bev[4] = {be.x, be.y, be.z, be.w};

    float* op = (float*)((char*)ws + EPI_SCR) +
                ((size_t)blockIdx.x * 4 + wave) * 32;

    for (int rep = 0; rep < 8; ++rep) {
        int nidx[8];
#pragma unroll
        for (int k = 0; k < 8; ++k)
            nidx[k] = (n * 7 + k * 293 + rep) & (NPTS - 1);   // fake, rep-varying

        float m16[4];
#pragma unroll
        for (int i = 0; i < 4; ++i) m16[i] = -__builtin_inff();
#pragma unroll
        for (int k = 0; k < 8; ++k) {
            float3 p = *(const float3*)(xb + 3 * nidx[k]);
            float gx = p.x - cx, gy = p.y - cy, gz = p.z - cz;
#pragma unroll
            for (int q = 0; q < 4; ++q) {
                float h = fmaf(gx, w[q][0], fmaf(gy, w[q][1], fmaf(gz, w[q][2], bev[q])));
                m16[k >> 1] = fmaxf(m16[k >> 1], h);
            }
        }

        float t[4], u[4];
#pragma unroll
        for (int i = 0; i < 4; ++i) {
            m16[i] = row16_max(m16[i]);
            t[i] = fmaxf(m16[i], __shfl_xor(m16[i], 16, 64));
            u[i] = fmaxf(t[i], __shfl_xor(t[i], 32, 64));
        }

        if ((lane & 15) == 0) {
            int j = lane >> 4;
#pragma unroll
            for (int i = 0; i < 4; ++i)
                op[i * 4 + j] = m16[i];
        }
        if (lane == 0 || lane == 32) {
            int j2 = lane >> 5;
            op[16 + 0 * 2 + j2] = fmaxf(t[0], t[1]);
            op[16 + 1 * 2 + j2] = fmaxf(t[2], t[3]);
        }
        if (lane == 0)
            op[20] = fmaxf(fmaxf(u[0], u[1]), fmaxf(u[2], u[3]));
        asm volatile("" ::: "memory");
    }
}

extern "C" void kernel_launch(void* const* d_in, const int* in_sizes, int n_in,
                              void* d_out, int out_size, void* d_ws, size_t ws_size,
                              hipStream_t stream) {
    const float* x  = (const float*)d_in[0];
    const float* w1 = (const float*)d_in[1];
    const float* b1 = (const float*)d_in[2];
    const float* w2 = (const float*)d_in[3];
    const float* b2 = (const float*)d_in[4];
    const float* w3 = (const float*)d_in[5];
    const float* b3 = (const float*)d_in[6];
    float* out = (float*)d_out;
    float* ws  = (float*)d_ws;

    int Bp = in_sizes[0] / (NPTS * 3);             // B*T = 4

    prep_sort_kernel<<<CCH / 2 + Bp, CCH, 0, stream>>>(
        x, w1, b1, w2, b2, w3, b3, ws, Bp);
    pointsift_kernel<<<Bp * (NPTS / 4), 256, 0, stream>>>(x, ws, out);
    // ---- diagnostic probes (write only ws scratch; removed next round) ----
    scan_probe_kernel<<<Bp * (NPTS / 4), 256, 0, stream>>>(x, ws);
    epi_probe_kernel<<<Bp * (NPTS / 4), 256, 0, stream>>>(x, ws);
}

// Round 14
// 22.423 us; speedup vs baseline: 4.3412x; 4.3412x over previous
//
#include <hip/hip_runtime.h>

#define NPTS 2048
#define CCH  256

// ws byte layout:
//   [0    .. 4095 ]  W_eff (256x3 f32) + b_eff (256 f32)
//   [4096 .. 6143 ]  starts: per batch 128 u32 slots (65 used)
//   [8192 .. 139263] scrd: float4[4][2048] cell-sorted (x,y,z,orig_idx_bits)
#define STARTS_OFF 4096
#define CRD_OFF    8192

// ---- DPP cross-lane helpers ----
template <int CTRL>
__device__ __forceinline__ float dppf(float v) {
    return __int_as_float(__builtin_amdgcn_update_dpp(
        0, __float_as_int(v), CTRL, 0xF, 0xF, true));
}
__device__ __forceinline__ float row16_max(float v) {
    v = fmaxf(v, dppf<0xB1>(v));
    v = fmaxf(v, dppf<0x4E>(v));
    v = fmaxf(v, dppf<0x141>(v));
    v = fmaxf(v, dppf<0x140>(v));
    return v;
}
__device__ __forceinline__ float row16_sum(float v) {
    v += dppf<0xB1>(v);
    v += dppf<0x4E>(v);
    v += dppf<0x141>(v);
    v += dppf<0x140>(v);
    return v;
}
__device__ __forceinline__ float wave_sum(float v) {
    v = row16_sum(v);
    v += __shfl_xor(v, 16, 64);
    v += __shfl_xor(v, 32, 64);
    return v;
}
__device__ __forceinline__ int cell_coord(float v) {
    int c = (int)(v * 4.0f);
    return min(3, max(0, c));
}

// ---------------------------------------------------------------------------
// Fused prep + per-batch counting sort (unchanged R12 structure).
// ---------------------------------------------------------------------------
__global__ __launch_bounds__(256) void prep_sort_kernel(
    const float* __restrict__ x,
    const float* __restrict__ w1, const float* __restrict__ b1,
    const float* __restrict__ w2, const float* __restrict__ b2,
    const float* __restrict__ w3, const float* __restrict__ b3,
    float* __restrict__ ws, int Bp)
{
    __shared__ float  w3row[2][CCH];
    __shared__ float4 wpart[2][4];
    __shared__ unsigned shist[64];
    __shared__ unsigned scur[64];

    int tid = threadIdx.x;

    if ((int)blockIdx.x < CCH / 2) {
        int o0 = blockIdx.x * 2, c = tid;
        float w3c0 = w3[(o0 + 0) * CCH + c];
        float w3c1 = w3[(o0 + 1) * CCH + c];
        w3row[0][c] = w3c0;
        w3row[1][c] = w3c1;
        __syncthreads();

        float a0 = 0.f, a1 = 0.f, a2 = 0.f, a3 = 0.f;
        float b0 = 0.f, b1p = 0.f, b2p = 0.f, b3p = 0.f;
        const float* w2c = w2 + c;
        for (int k = 0; k < CCH; k += 4) {
            float q0 = w2c[(k + 0) * CCH];
            float q1 = w2c[(k + 1) * CCH];
            float q2 = w2c[(k + 2) * CCH];
            float q3 = w2c[(k + 3) * CCH];
            a0 = fmaf(w3row[0][k + 0], q0, a0);
            a1 = fmaf(w3row[0][k + 1], q1, a1);
            a2 = fmaf(w3row[0][k + 2], q2, a2);
            a3 = fmaf(w3row[0][k + 3], q3, a3);
            b0  = fmaf(w3row[1][k + 0], q0, b0);
            b1p = fmaf(w3row[1][k + 1], q1, b1p);
            b2p = fmaf(w3row[1][k + 2], q2, b2p);
            b3p = fmaf(w3row[1][k + 3], q3, b3p);
        }
        float accA = (a0 + a1) + (a2 + a3);
        float accB = (b0 + b1p) + (b2p + b3p);

        float w1x = w1[c * 3 + 0], w1y = w1[c * 3 + 1], w1z = w1[c * 3 + 2];
        float b1c = b1[c], b2c = b2[c];

        float4 vA = make_float4(accA * w1x, accA * w1y, accA * w1z,
                                fmaf(accA, b1c, w3c0 * b2c));
        float4 vB = make_float4(accB * w1x, accB * w1y, accB * w1z,
                                fmaf(accB, b1c, w3c1 * b2c));
        vA.x = wave_sum(vA.x); vA.y = wave_sum(vA.y);
        vA.z = wave_sum(vA.z); vA.w = wave_sum(vA.w);
        vB.x = wave_sum(vB.x); vB.y = wave_sum(vB.y);
        vB.z = wave_sum(vB.z); vB.w = wave_sum(vB.w);
        if ((c & 63) == 0) {
            wpart[0][c >> 6] = vA;
            wpart[1][c >> 6] = vB;
        }
        __syncthreads();
        if (c < 2) {
            int o = o0 + c;
            float4 p0 = wpart[c][0], p1 = wpart[c][1], p2 = wpart[c][2], p3 = wpart[c][3];
            ws[o * 3 + 0] = (p0.x + p1.x) + (p2.x + p3.x);
            ws[o * 3 + 1] = (p0.y + p1.y) + (p2.y + p3.y);
            ws[o * 3 + 2] = (p0.z + p1.z) + (p2.z + p3.z);
            ws[3 * CCH + o] = (p0.w + p1.w) + (p2.w + p3.w) + b3[o];
        }
        return;
    }

    int b = blockIdx.x - CCH / 2;
    if (b >= Bp) return;
    const float* xb = x + (size_t)b * NPTS * 3;

    if (tid < 64) shist[tid] = 0;
    __syncthreads();

    float a[24];
#pragma unroll
    for (int j = 0; j < 6; ++j)
        *(float4*)(a + 4 * j) = ((const float4*)xb)[tid * 6 + j];

    int cl[8];
#pragma unroll
    for (int k = 0; k < 8; ++k) {
        cl[k] = (cell_coord(a[3 * k + 0]) << 4) |
                (cell_coord(a[3 * k + 1]) << 2) |
                 cell_coord(a[3 * k + 2]);
        atomicAdd(&shist[cl[k]], 1u);
    }
    __syncthreads();

    unsigned* stg = (unsigned*)((char*)ws + STARTS_OFF) + b * 128;
    if (tid < 64) {
        unsigned v = shist[tid];
        unsigned incl = v;
#pragma unroll
        for (int s = 1; s < 64; s <<= 1) {
            unsigned o = __shfl_up(incl, s, 64);
            if (tid >= s) incl += o;
        }
        unsigned excl = incl - v;
        scur[tid] = excl;
        stg[tid] = excl;
        if (tid == 63) stg[64] = NPTS;
    }
    __syncthreads();

    float4* crd = (float4*)((char*)ws + CRD_OFF) + (size_t)b * NPTS;
#pragma unroll
    for (int k = 0; k < 8; ++k) {
        unsigned pos = atomicAdd(&scur[cl[k]], 1u);
        crd[pos] = make_float4(a[3 * k + 0], a[3 * k + 1], a[3 * k + 2],
                               __uint_as_float((unsigned)(8 * tid + k)));
    }
}

// ---------------------------------------------------------------------------
// pointsift: 256 threads = 4 waves = 4 points/block; 3-slab scan with 2-deep
// load pipelining (two b128 loads in flight per iteration -> attacks the 55%
// memory-latency stall the R13 probe measured). Weights hoisted pre-scan.
// Selection: ds_min_u64 lex keys (order-independent, numpy-first-min-exact).
// ---------------------------------------------------------------------------
__global__ __launch_bounds__(256, 8) void pointsift_kernel(
    const float* __restrict__ x,
    const float* __restrict__ ws,
    float* __restrict__ out)
{
    __shared__ unsigned sstart[65];
    __shared__ unsigned long long soct[4][8];

    int tid = threadIdx.x;
    int batch = blockIdx.x & 3;
    int n0    = (blockIdx.x >> 2) * 4;
    const float* xb = x + (size_t)batch * NPTS * 3;
    const float4* crd = (const float4*)((const char*)ws + CRD_OFF) + (size_t)batch * NPTS;
    const unsigned* stg = (const unsigned*)((const char*)ws + STARTS_OFF) + batch * 128;

    if (tid < 65) sstart[tid] = stg[tid];

    int wave = tid >> 6;
    int lane = tid & 63;
    int n = n0 + wave;

    float3 cpt = *(const float3*)(xb + 3 * n);
    float cx = cpt.x, cy = cpt.y, cz = cpt.z;

    if (lane < 8)
        soct[wave][lane] = (0x7f800000ULL << 32) | (unsigned)n;

    // hoist epilogue weight/bias loads: ~400 instrs of latency slack
    const float4* wsv = (const float4*)ws;
    float4 wa = wsv[lane * 3 + 0];
    float4 wb = wsv[lane * 3 + 1];
    float4 wc = wsv[lane * 3 + 2];
    float4 be = ((const float4*)(ws + 3 * CCH))[lane];

    __syncthreads();

    int ccx = cell_coord(cx), ccy = cell_coord(cy);
    int alo = ccx > 0 ? ccx - 1 : 0;
    int ahi = ccx < 3 ? ccx + 1 : 3;
    int bclo = ccy > 0 ? ccy - 1 : 0;
    int bchi = ccy < 3 ? ccy + 1 : 3;

    for (int a = alo; a <= ahi; ++a) {
        unsigned s0 = sstart[(a << 4) | (bclo << 2)];
        unsigned e0 = sstart[(a << 4) + (bchi << 2) + 4];
        unsigned pp = s0 + lane;
        // 2-deep pipelined scan: two independent loads per iteration
        for (; pp + 64 < e0; pp += 128) {
            float4 p  = crd[pp];
            float4 p2 = crd[pp + 64];
            {
                float dx = p.x - cx, dy = p.y - cy, dz = p.z - cz;
                float d2 = __fadd_rn(__fadd_rn(__fmul_rn(dx, dx), __fmul_rn(dy, dy)),
                                     __fmul_rn(dz, dz));
                if ((d2 > 1e-10f) && (d2 < 0.0625f)) {
                    int oct = 4 * (int)(dx + 1.0f) + 2 * (int)(dy + 1.0f) + (int)(dz + 1.0f);
                    unsigned long long key =
                        ((unsigned long long)__float_as_uint(d2) << 32) |
                        __float_as_uint(p.w);
                    __hip_atomic_fetch_min(&soct[wave][oct], key,
                                           __ATOMIC_RELAXED,
                                           __HIP_MEMORY_SCOPE_WORKGROUP);
                }
            }
            {
                float dx = p2.x - cx, dy = p2.y - cy, dz = p2.z - cz;
                float d2 = __fadd_rn(__fadd_rn(__fmul_rn(dx, dx), __fmul_rn(dy, dy)),
                                     __fmul_rn(dz, dz));
                if ((d2 > 1e-10f) && (d2 < 0.0625f)) {
                    int oct = 4 * (int)(dx + 1.0f) + 2 * (int)(dy + 1.0f) + (int)(dz + 1.0f);
                    unsigned long long key =
                        ((unsigned long long)__float_as_uint(d2) << 32) |
                        __float_as_uint(p2.w);
                    __hip_atomic_fetch_min(&soct[wave][oct], key,
                                           __ATOMIC_RELAXED,
                                           __HIP_MEMORY_SCOPE_WORKGROUP);
                }
            }
        }
        if (pp < e0) {
            float4 p = crd[pp];
            float dx = p.x - cx, dy = p.y - cy, dz = p.z - cz;
            float d2 = __fadd_rn(__fadd_rn(__fmul_rn(dx, dx), __fmul_rn(dy, dy)),
                                 __fmul_rn(dz, dz));
            if ((d2 > 1e-10f) && (d2 < 0.0625f)) {
                int oct = 4 * (int)(dx + 1.0f) + 2 * (int)(dy + 1.0f) + (int)(dz + 1.0f);
                unsigned long long key =
                    ((unsigned long long)__float_as_uint(d2) << 32) |
                    __float_as_uint(p.w);
                __hip_atomic_fetch_min(&soct[wave][oct], key,
                                       __ATOMIC_RELAXED,
                                       __HIP_MEMORY_SCOPE_WORKGROUP);
            }
        }
    }

    int nidx[8];
#pragma unroll
    for (int k = 0; k < 8; ++k)
        nidx[k] = (int)(unsigned)soct[wave][k];

    float w[4][3] = {{wa.x, wa.y, wa.z}, {wa.w, wb.x, wb.y},
                     {wb.z, wb.w, wc.x}, {wc.y, wc.z, wc.w}};
    float bev[4] = {be.x, be.y, be.z, be.w};

    float m16[4];
#pragma unroll
    for (int i = 0; i < 4; ++i) m16[i] = -__builtin_inff();
#pragma unroll
    for (int k = 0; k < 8; ++k) {
        float3 p = *(const float3*)(xb + 3 * nidx[k]);
        float gx = p.x - cx, gy = p.y - cy, gz = p.z - cz;
#pragma unroll
        for (int q = 0; q < 4; ++q) {
            float h = fmaf(gx, w[q][0], fmaf(gy, w[q][1], fmaf(gz, w[q][2], bev[q])));
            m16[k >> 1] = fmaxf(m16[k >> 1], h);
        }
    }

    float t[4], u[4];
#pragma unroll
    for (int i = 0; i < 4; ++i) {
        m16[i] = row16_max(m16[i]);
        t[i] = fmaxf(m16[i], __shfl_xor(m16[i], 16, 64));
        u[i] = fmaxf(t[i], __shfl_xor(t[i], 32, 64));
    }

    float* op = out + ((size_t)batch * NPTS + n) * 21;
    if ((lane & 15) == 0) {
        int j = lane >> 4;
#pragma unroll
        for (int i = 0; i < 4; ++i)
            op[i * 4 + j] = m16[i];
    }
    if (lane == 0 || lane == 32) {
        int j2 = lane >> 5;
        op[16 + 0 * 2 + j2] = fmaxf(t[0], t[1]);
        op[16 + 1 * 2 + j2] = fmaxf(t[2], t[3]);
    }
    if (lane == 0) {
        op[20] = fmaxf(fmaxf(u[0], u[1]), fmaxf(u[2], u[3]));
    }
}

extern "C" void kernel_launch(void* const* d_in, const int* in_sizes, int n_in,
                              void* d_out, int out_size, void* d_ws, size_t ws_size,
                              hipStream_t stream) {
    const float* x  = (const float*)d_in[0];
    const float* w1 = (const float*)d_in[1];
    const float* b1 = (const float*)d_in[2];
    const float* w2 = (const float*)d_in[3];
    const float* b2 = (const float*)d_in[4];
    const float* w3 = (const float*)d_in[5];
    const float* b3 = (const float*)d_in[6];
    float* out = (float*)d_out;
    float* ws  = (float*)d_ws;

    int Bp = in_sizes[0] / (NPTS * 3);             // B*T = 4

    prep_sort_kernel<<<CCH / 2 + Bp, CCH, 0, stream>>>(
        x, w1, b1, w2, b2, w3, b3, ws, Bp);
    pointsift_kernel<<<Bp * (NPTS / 4), 256, 0, stream>>>(x, ws, out);
}